// Round 1
// baseline (2748.545 us; speedup 1.0000x reference)
//
#include <hip/hip_runtime.h>

#define S   9216    // 96*96
#define HW  96
#define CIN 64
#define QC  576     // CIN*9
#define BATCH_XO (QC * S)   // 5,308,416 floats per batch image
#define OW  94
#define WSZ 5184    // 576*9 weights per output channel

__device__ __forceinline__ float samp(const float* __restrict__ xc, int iy, int ix) {
    // padded coords in [0,98); interior rows/cols are [1,96]
    if (iy >= 1 && iy <= HW && ix >= 1 && ix <= HW)
        return xc[(iy - 1) * HW + (ix - 1)];
    return 0.0f;
}

__global__ __launch_bounds__(256)
void gather_k(const float* __restrict__ x,
              const float* __restrict__ off,
              float* __restrict__ xo,
              int b0, int total) {
    int idx = blockIdx.x * blockDim.x + threadIdx.x;
    if (idx >= total) return;
    int bl  = idx / (8 * S);
    int rem = idx - bl * (8 * S);
    int cig = rem / S;
    int r   = rem - cig * S;
    int b   = b0 + bl;
    const float* ob = off + (size_t)b * 18 * S;

    // Decode the 9 (qx,qy) pairs for this spatial position r (torch-scrambled layout):
    // channel k, pos r -> f = k*S + r; n = f/(2S); t = f mod 2S; comp = t&1; pos = t>>1.
    int ix0[9], iy0[9];
    float fx[9], fy[9];
    #pragma unroll
    for (int m = 0; m < 9; ++m) {
        float q[2];
        #pragma unroll
        for (int c2 = 0; c2 < 2; ++c2) {
            int k = m + 9 * c2;
            int f = k * S + r;
            int nn = f / (2 * S);
            int t  = f - nn * (2 * S);
            int comp = t & 1;
            int pos  = t >> 1;
            float g = comp ? (float)(nn % 3) : (float)(nn / 3);
            q[c2] = g + ob[(2 * nn + comp) * S + pos];
        }
        float qx = fminf(fmaxf(q[0], 0.f), 97.f);
        float qy = fminf(fmaxf(q[1], 0.f), 97.f);
        int x0 = (int)qx; if (x0 > 97) x0 = 97;
        int y0 = (int)qy; if (y0 > 97) y0 = 97;
        ix0[m] = x0; iy0[m] = y0;
        fx[m] = qx - (float)x0;
        fy[m] = qy - (float)y0;
    }

    const float* xb = x + (size_t)b * CIN * S;
    float* outb = xo + (size_t)bl * BATCH_XO + (size_t)r * 9;
    for (int i = 0; i < 8; ++i) {
        int ci = cig * 8 + i;
        const float* xc = xb + (size_t)ci * S;
        float* o9 = outb + (size_t)ci * (9 * S);
        #pragma unroll
        for (int m = 0; m < 9; ++m) {
            int x0 = ix0[m], y0 = iy0[m];
            int x1 = x0 + 1; if (x1 > 97) x1 = 97;
            int y1 = y0 + 1; if (y1 > 97) y1 = 97;
            float v00 = samp(xc, y0, x0);
            float v01 = samp(xc, y0, x1);
            float v10 = samp(xc, y1, x0);
            float v11 = samp(xc, y1, x1);
            float a = fx[m], c = fy[m];
            float top = v00 + (v01 - v00) * a;
            float bot = v10 + (v11 - v10) * a;
            o9[m] = top + (bot - top) * c;
        }
    }
}

// Direct 3x3 conv over the scrambled xo: each thread computes 4 consecutive ox
// for one output channel o. block = (24 oxb, 8 ol), grid = (8 og, 94 oy, nb).
__global__ __launch_bounds__(192)
void conv_k(const float* __restrict__ xo,
            const float* __restrict__ w,
            const float* __restrict__ bias,
            float* __restrict__ out,
            int b0) {
    int oxb = threadIdx.x;        // 0..23 -> ox base = oxb*4
    int ol  = threadIdx.y;        // 0..7
    int og  = blockIdx.x;         // 0..7
    int oy  = blockIdx.y;         // 0..93
    int bl  = blockIdx.z;
    int o   = og * 8 + ol;
    int b   = b0 + bl;

    const float* wq  = w + (size_t)o * WSZ;
    const float* xb  = xo + (size_t)bl * BATCH_XO + (size_t)oy * HW + oxb * 4;
    // float2 tail: for oxb==23 those values only feed masked (ox>=94) outputs,
    // so clamp the pointer back to stay in-bounds.
    const float* xb2 = xb + ((oxb < 23) ? 4 : 0);

    float acc0 = 0.f, acc1 = 0.f, acc2 = 0.f, acc3 = 0.f;
    for (int q = 0; q < QC; ++q) {
        const float* xq  = xb  + (size_t)q * S;
        const float* xq2 = xb2 + (size_t)q * S;
        const float* wk  = wq + q * 9;
        #pragma unroll
        for (int ky = 0; ky < 3; ++ky) {
            float4 v4 = *reinterpret_cast<const float4*>(xq + ky * HW);
            float2 v2 = *reinterpret_cast<const float2*>(xq2 + ky * HW);
            float w0 = wk[ky * 3 + 0];
            float w1 = wk[ky * 3 + 1];
            float w2 = wk[ky * 3 + 2];
            acc0 += v4.x * w0 + v4.y * w1 + v4.z * w2;
            acc1 += v4.y * w0 + v4.z * w1 + v4.w * w2;
            acc2 += v4.z * w0 + v4.w * w1 + v2.x * w2;
            acc3 += v4.w * w0 + v2.x * w1 + v2.y * w2;
        }
    }
    float bi = bias[o];
    int ox = oxb * 4;
    float* ob = out + (((size_t)b * 64 + o) * OW + oy) * OW + ox;
    if (ox + 0 < OW) ob[0] = acc0 + bi;
    if (ox + 1 < OW) ob[1] = acc1 + bi;
    if (ox + 2 < OW) ob[2] = acc2 + bi;
    if (ox + 3 < OW) ob[3] = acc3 + bi;
}

extern "C" void kernel_launch(void* const* d_in, const int* in_sizes, int n_in,
                              void* d_out, int out_size, void* d_ws, size_t ws_size,
                              hipStream_t stream) {
    const float* x    = (const float*)d_in[0];
    const float* off  = (const float*)d_in[1];
    const float* w    = (const float*)d_in[2];
    const float* bias = (const float*)d_in[3];
    float* out = (float*)d_out;
    float* ws  = (float*)d_ws;

    const size_t per_batch_bytes = (size_t)BATCH_XO * sizeof(float); // 21.2 MB
    int nbmax = (int)(ws_size / per_batch_bytes);
    if (nbmax < 1) nbmax = 1;
    if (nbmax > 8) nbmax = 8;

    for (int b0 = 0; b0 < 8; b0 += nbmax) {
        int nb = (8 - b0 < nbmax) ? (8 - b0) : nbmax;
        int total = nb * 8 * S;
        gather_k<<<(total + 255) / 256, 256, 0, stream>>>(x, off, ws, b0, total);
        conv_k<<<dim3(8, 94, nb), dim3(24, 8), 0, stream>>>(ws, w, bias, out, b0);
    }
}

// Round 2
// 302.007 us; speedup vs baseline: 9.1009x; 9.1009x over previous
//
#include <hip/hip_runtime.h>

typedef short bf16x8 __attribute__((ext_vector_type(8)));
typedef float f32x4  __attribute__((ext_vector_type(4)));

#define Sx 9216          // 96*96
#define ROWW 104         // padded x width of xo_t
#define RSTRIDE (ROWW*576)   // elems per (b,y) row of xo_t
#define WB_USHORTS 331776    // 162 steps * 4 mt * 64 lanes * 8
#define OW 94

__device__ __forceinline__ unsigned short bf16r(float f) {
    unsigned int u = __float_as_uint(f);
    u += 0x7fffu + ((u >> 16) & 1u);
    return (unsigned short)(u >> 16);
}

__device__ __forceinline__ void gload16(const void* g, void* l) {
    __builtin_amdgcn_global_load_lds(
        (const __attribute__((address_space(1))) void*)g,
        (__attribute__((address_space(3))) void*)l, 16, 0, 0);
}

// ---- Weight prep: fp32 conv_w -> bf16 in MFMA A-fragment order ----
// step = qc*18 + t*2 + q32 ; element (step, mt, lane, j):
//   o = mt*16 + (lane&15), q = qc*64 + q32*32 + (lane>>4)*8 + j, tap t
__global__ __launch_bounds__(256)
void wprep_k(const float* __restrict__ w, unsigned short* __restrict__ Wb) {
    int id = blockIdx.x * 256 + threadIdx.x;       // 0..41471
    if (id >= 162 * 4 * 64) return;
    int lane = id & 63;
    int fm   = id >> 6;          // step*4 + mt
    int mt   = fm & 3;
    int step = fm >> 2;
    int qc   = step / 18;
    int rs   = step - qc * 18;
    int t    = rs >> 1;
    int q32  = rs & 1;
    int o    = mt * 16 + (lane & 15);
    int qb   = qc * 64 + q32 * 32 + (lane >> 4) * 8;
    unsigned short v[8];
    #pragma unroll
    for (int j = 0; j < 8; ++j)
        v[j] = bf16r(w[(size_t)o * 5184 + (qb + j) * 9 + t]);
    uint4 u;
    u.x = v[0] | ((unsigned)v[1] << 16);
    u.y = v[2] | ((unsigned)v[3] << 16);
    u.z = v[4] | ((unsigned)v[5] << 16);
    u.w = v[6] | ((unsigned)v[7] << 16);
    *(uint4*)(Wb + (size_t)id * 8) = u;
}

// ---- Gather: deformable bilinear sample -> xo_t[b][y][x(104)][ch(576)] bf16
// Scrambled mapping: NCHW (ch,y,x): ci=ch/9, chr=ch%9, rem=chr*9216+y*96+x,
// r=rem/9 (sample spatial pos), n=rem%9 (tap). Coord decode identical to the
// verified round-0 kernel (k = n + 9*c2 path).
__global__ __launch_bounds__(256)
void gather_k(const float* __restrict__ x, const float* __restrict__ off,
              unsigned short* __restrict__ xo) {
    int idx = blockIdx.x * 256 + threadIdx.x;   // 0..73727 per batch
    int b   = blockIdx.y;
    int xc_ = idx % 96;            // lanes consecutive in x -> tap-load locality
    int g   = (idx / 96) & 7;      // ci group (8 ci each)
    int y   = idx / 768;

    const float* ob = off + (size_t)b * 18 * Sx;
    const float* xb = x   + (size_t)b * 64 * Sx;
    int r2 = y * 96 + xc_;

    unsigned short vb[72];
    #pragma unroll
    for (int chr = 0; chr < 9; ++chr) {
        int rem = chr * Sx + r2;
        int r   = rem / 9;
        int n   = rem - r * 9;
        float q2[2];
        #pragma unroll
        for (int c2 = 0; c2 < 2; ++c2) {
            int k    = n + 9 * c2;
            int f    = k * Sx + r;
            int nn   = f / 18432;
            int t    = f - nn * 18432;
            int comp = t & 1;
            int pos  = t >> 1;
            int nd3  = nn / 3;
            float gg = comp ? (float)(nn - nd3 * 3) : (float)nd3;
            q2[c2] = gg + ob[(size_t)(2 * nn + comp) * Sx + pos];
        }
        float qx = fminf(fmaxf(q2[0], 0.f), 97.f);
        float qy = fminf(fmaxf(q2[1], 0.f), 97.f);
        int x0 = (int)qx; if (x0 > 97) x0 = 97;
        int y0 = (int)qy; if (y0 > 97) y0 = 97;
        float fx = qx - (float)x0;
        float fy = qy - (float)y0;
        int x1 = x0 + 1; if (x1 > 97) x1 = 97;
        int y1 = y0 + 1; if (y1 > 97) y1 = 97;
        // padded->unpadded: valid iff 1..96
        int ix0 = x0 - 1, ix1 = x1 - 1, iy0 = y0 - 1, iy1 = y1 - 1;
        float vx0 = (ix0 >= 0 && ix0 < 96) ? 1.f : 0.f;
        float vx1 = (ix1 >= 0 && ix1 < 96) ? 1.f : 0.f;
        float vy0 = (iy0 >= 0 && iy0 < 96) ? 1.f : 0.f;
        float vy1 = (iy1 >= 0 && iy1 < 96) ? 1.f : 0.f;
        int cx0 = min(max(ix0, 0), 95), cx1 = min(max(ix1, 0), 95);
        int cy0 = min(max(iy0, 0), 95), cy1 = min(max(iy1, 0), 95);
        float w00 = (1.f - fx) * (1.f - fy) * vx0 * vy0;
        float w01 = fx * (1.f - fy) * vx1 * vy0;
        float w10 = (1.f - fx) * fy * vx0 * vy1;
        float w11 = fx * fy * vx1 * vy1;
        int a00 = cy0 * 96 + cx0, a01 = cy0 * 96 + cx1;
        int a10 = cy1 * 96 + cx0, a11 = cy1 * 96 + cx1;
        #pragma unroll
        for (int i = 0; i < 8; ++i) {
            const float* xch = xb + (size_t)(g * 8 + i) * Sx;
            float v = w00 * xch[a00] + w01 * xch[a01]
                    + w10 * xch[a10] + w11 * xch[a11];
            vb[i * 9 + chr] = bf16r(v);
        }
    }
    // write 72 contiguous bf16 (channels g*72 .. g*72+71) as 9 x uint4
    uint4* dst = (uint4*)(xo + ((size_t)(b * 96 + y) * ROWW + xc_) * 576 + g * 72);
    #pragma unroll
    for (int a = 0; a < 9; ++a) {
        uint4 u;
        u.x = vb[8*a+0] | ((unsigned)vb[8*a+1] << 16);
        u.y = vb[8*a+2] | ((unsigned)vb[8*a+3] << 16);
        u.z = vb[8*a+4] | ((unsigned)vb[8*a+5] << 16);
        u.w = vb[8*a+6] | ((unsigned)vb[8*a+7] << 16);
        dst[a] = u;
    }
}

// ---- Conv as implicit GEMM on MFMA ----
// Block: 3 waves, one oy row, C-tile 64(o) x 96(px). K = 9 taps * 576 q.
// Per q-chunk (64 q): LDS tile [ky 0..2][x 0..103][q 0..63] bf16, staged by
// global_load_lds(16B) with XOR-swizzled global source (slot s at x holds
// q-block s^(x&7)); B-frag ds_read_b128 applies the same XOR -> ~conflict-free.
__global__ __launch_bounds__(192, 4)
void conv_mfma(const unsigned short* __restrict__ xo,
               const unsigned short* __restrict__ Wb,
               const float* __restrict__ bias,
               float* __restrict__ out) {
    const int lane = threadIdx.x & 63;
    const int wn   = threadIdx.x >> 6;   // 0..2 (= staged ky row)
    const int oy   = blockIdx.x;         // 0..93
    const int b    = blockIdx.y;

    __shared__ unsigned short tile[3 * ROWW * 64];   // 39936 B
    char* tb = (char*)tile;

    f32x4 acc[4][2];
    #pragma unroll
    for (int m = 0; m < 4; ++m)
        #pragma unroll
        for (int nfl = 0; nfl < 2; ++nfl)
            acc[m][nfl] = (f32x4){0.f, 0.f, 0.f, 0.f};

    const bf16x8* W8 = (const bf16x8*)Wb;

    const int xl  = lane >> 3;          // 0..7
    const int sl  = lane & 7;
    const int swz = (sl ^ xl) * 8;      // pre-swizzled q-slot (elems)
    const size_t growbase = ((size_t)(b * 96 + oy + wn) * ROWW) * 576;
    unsigned short* lrow = tile + wn * (ROWW * 64);   // this wave stages row ky=wn

    for (int qc = 0; qc < 9; ++qc) {
        if (qc) __syncthreads();
        #pragma unroll
        for (int i = 0; i < 13; ++i) {
            const unsigned short* src =
                xo + growbase + (size_t)(i * 8 + xl) * 576 + qc * 64 + swz;
            gload16(src, lrow + i * 512);   // + lane*16B implicit
        }
        asm volatile("s_waitcnt vmcnt(0)" ::: "memory");
        __syncthreads();

        #pragma unroll
        for (int t = 0; t < 9; ++t) {
            const int ky = t / 3, kx = t - (t / 3) * 3;
            #pragma unroll
            for (int q32 = 0; q32 < 2; ++q32) {
                const int step = qc * 18 + t * 2 + q32;
                bf16x8 a0 = W8[(step * 4 + 0) * 64 + lane];
                bf16x8 a1 = W8[(step * 4 + 1) * 64 + lane];
                bf16x8 a2 = W8[(step * 4 + 2) * 64 + lane];
                bf16x8 a3 = W8[(step * 4 + 3) * 64 + lane];
                bf16x8 bf[2];
                #pragma unroll
                for (int nfl = 0; nfl < 2; ++nfl) {
                    int xpix = (wn * 2 + nfl) * 16 + (lane & 15) + kx;
                    int slot = (q32 * 4 + (lane >> 4)) ^ (xpix & 7);
                    bf[nfl] = *(const bf16x8*)(tb + ky * 13312 + xpix * 128 + slot * 16);
                }
                acc[0][0] = __builtin_amdgcn_mfma_f32_16x16x32_bf16(a0, bf[0], acc[0][0], 0, 0, 0);
                acc[0][1] = __builtin_amdgcn_mfma_f32_16x16x32_bf16(a0, bf[1], acc[0][1], 0, 0, 0);
                acc[1][0] = __builtin_amdgcn_mfma_f32_16x16x32_bf16(a1, bf[0], acc[1][0], 0, 0, 0);
                acc[1][1] = __builtin_amdgcn_mfma_f32_16x16x32_bf16(a1, bf[1], acc[1][1], 0, 0, 0);
                acc[2][0] = __builtin_amdgcn_mfma_f32_16x16x32_bf16(a2, bf[0], acc[2][0], 0, 0, 0);
                acc[2][1] = __builtin_amdgcn_mfma_f32_16x16x32_bf16(a2, bf[1], acc[2][1], 0, 0, 0);
                acc[3][0] = __builtin_amdgcn_mfma_f32_16x16x32_bf16(a3, bf[0], acc[3][0], 0, 0, 0);
                acc[3][1] = __builtin_amdgcn_mfma_f32_16x16x32_bf16(a3, bf[1], acc[3][1], 0, 0, 0);
            }
        }
    }

    // Epilogue: C/D layout col=lane&15 (pixel), row=(lane>>4)*4+j (o in tile)
    #pragma unroll
    for (int m = 0; m < 4; ++m) {
        #pragma unroll
        for (int nfl = 0; nfl < 2; ++nfl) {
            int ox = (wn * 2 + nfl) * 16 + (lane & 15);
            if (ox < OW) {
                #pragma unroll
                for (int j = 0; j < 4; ++j) {
                    int o = m * 16 + (lane >> 4) * 4 + j;
                    out[(((size_t)b * 64 + o) * OW + oy) * OW + ox] = acc[m][nfl][j] + bias[o];
                }
            }
        }
    }
}

extern "C" void kernel_launch(void* const* d_in, const int* in_sizes, int n_in,
                              void* d_out, int out_size, void* d_ws, size_t ws_size,
                              hipStream_t stream) {
    const float* x    = (const float*)d_in[0];
    const float* off  = (const float*)d_in[1];
    const float* w    = (const float*)d_in[2];
    const float* bias = (const float*)d_in[3];
    unsigned short* ws16 = (unsigned short*)d_ws;
    unsigned short* Wb   = ws16;                  // 663,552 B
    unsigned short* xo   = ws16 + WB_USHORTS;     // 8*96*104*576*2 = 92.0 MB

    wprep_k<<<162, 256, 0, stream>>>(w, Wb);
    gather_k<<<dim3(288, 8), 256, 0, stream>>>(x, off, xo);
    conv_mfma<<<dim3(94, 8), 192, 0, stream>>>(xo, Wb, bias, (float*)d_out);
}

// Round 3
// 291.483 us; speedup vs baseline: 9.4295x; 1.0361x over previous
//
#include <hip/hip_runtime.h>

typedef short bf16x8 __attribute__((ext_vector_type(8)));
typedef float f32x4  __attribute__((ext_vector_type(4)));

#define Sx 9216          // 96*96
#define ROWW 104         // padded x width of xo_t
#define WB_USHORTS 331776    // 162 steps * 4 mt * 64 lanes * 8
#define OW 94

__device__ __forceinline__ unsigned short bf16r(float f) {
    unsigned int u = __float_as_uint(f);
    u += 0x7fffu + ((u >> 16) & 1u);
    return (unsigned short)(u >> 16);
}

__device__ __forceinline__ void gload16(const void* g, void* l) {
    __builtin_amdgcn_global_load_lds(
        (const __attribute__((address_space(1))) void*)g,
        (__attribute__((address_space(3))) void*)l, 16, 0, 0);
}

// ---- Weight prep: fp32 conv_w -> bf16 in MFMA A-fragment order ----
__global__ __launch_bounds__(256)
void wprep_k(const float* __restrict__ w, unsigned short* __restrict__ Wb) {
    int id = blockIdx.x * 256 + threadIdx.x;       // 0..41471
    if (id >= 162 * 4 * 64) return;
    int lane = id & 63;
    int fm   = id >> 6;          // step*4 + mt
    int mt   = fm & 3;
    int step = fm >> 2;
    int qc   = step / 18;
    int rs   = step - qc * 18;
    int t    = rs >> 1;
    int q32  = rs & 1;
    int o    = mt * 16 + (lane & 15);
    int qb   = qc * 64 + q32 * 32 + (lane >> 4) * 8;
    unsigned short v[8];
    #pragma unroll
    for (int j = 0; j < 8; ++j)
        v[j] = bf16r(w[(size_t)o * 5184 + (qb + j) * 9 + t]);
    uint4 u;
    u.x = v[0] | ((unsigned)v[1] << 16);
    u.y = v[2] | ((unsigned)v[3] << 16);
    u.z = v[4] | ((unsigned)v[5] << 16);
    u.w = v[6] | ((unsigned)v[7] << 16);
    *(uint4*)(Wb + (size_t)id * 8) = u;
}

// ---- Gather: block = (b, y, 32-x strip); phase 1 builds a shared decode
// table (4 addrs + 4 fused weights per (x,chr)); phase 2 = pure loads+FMA.
__global__ __launch_bounds__(256, 2)
void gather_k(const float* __restrict__ x, const float* __restrict__ off,
              unsigned short* __restrict__ xo) {
    __shared__ int   sA[4][288];
    __shared__ float sW[4][288];

    const int tid = threadIdx.x;
    const int x0b = blockIdx.x * 32;
    const int y   = blockIdx.y;
    const int b   = blockIdx.z;
    const float* ob = off + (size_t)b * 18 * Sx;

    // ---- phase 1: decode 288 entries (chr 0..8  x  32 x-positions) ----
    for (int e = tid; e < 288; e += 256) {
        int chr = e >> 5;
        int xl  = e & 31;
        int r2  = y * 96 + x0b + xl;
        int n   = r2 % 9;                 // 9216 % 9 == 0
        int r   = chr * 1024 + r2 / 9;
        float q2[2];
        #pragma unroll
        for (int c2 = 0; c2 < 2; ++c2) {
            int k    = n + 9 * c2;
            int f    = k * Sx + r;
            int nn   = f / 18432;
            int t    = f - nn * 18432;
            int comp = t & 1;
            int pos  = t >> 1;
            int nd3  = nn / 3;
            float gg = comp ? (float)(nn - nd3 * 3) : (float)nd3;
            q2[c2] = gg + ob[(size_t)(2 * nn + comp) * Sx + pos];
        }
        float qx = fminf(fmaxf(q2[0], 0.f), 97.f);
        float qy = fminf(fmaxf(q2[1], 0.f), 97.f);
        int x0 = (int)qx; if (x0 > 97) x0 = 97;
        int y0 = (int)qy; if (y0 > 97) y0 = 97;
        float fx = qx - (float)x0;
        float fy = qy - (float)y0;
        int x1 = x0 + 1; if (x1 > 97) x1 = 97;
        int y1 = y0 + 1; if (y1 > 97) y1 = 97;
        int ix0 = x0 - 1, ix1 = x1 - 1, iy0 = y0 - 1, iy1 = y1 - 1;
        float vx0 = (ix0 >= 0 && ix0 < 96) ? 1.f : 0.f;
        float vx1 = (ix1 >= 0 && ix1 < 96) ? 1.f : 0.f;
        float vy0 = (iy0 >= 0 && iy0 < 96) ? 1.f : 0.f;
        float vy1 = (iy1 >= 0 && iy1 < 96) ? 1.f : 0.f;
        int cx0 = min(max(ix0, 0), 95), cx1 = min(max(ix1, 0), 95);
        int cy0 = min(max(iy0, 0), 95), cy1 = min(max(iy1, 0), 95);
        sW[0][e] = (1.f - fx) * (1.f - fy) * vx0 * vy0;
        sW[1][e] = fx * (1.f - fy) * vx1 * vy0;
        sW[2][e] = (1.f - fx) * fy * vx0 * vy1;
        sW[3][e] = fx * fy * vx1 * vy1;
        sA[0][e] = cy0 * 96 + cx0;
        sA[1][e] = cy0 * 96 + cx1;
        sA[2][e] = cy1 * 96 + cx0;
        sA[3][e] = cy1 * 96 + cx1;
    }
    __syncthreads();

    // ---- phase 2: 8 ci x 9 chr bilinear combines per thread ----
    const int xl = tid & 31;
    const int g  = tid >> 5;
    const float* xb = x + (size_t)b * 64 * Sx + (size_t)g * 8 * Sx;

    unsigned short vb[72];
    #pragma unroll
    for (int chr = 0; chr < 9; ++chr) {
        int e = chr * 32 + xl;
        int   a00 = sA[0][e], a01 = sA[1][e], a10 = sA[2][e], a11 = sA[3][e];
        float w00 = sW[0][e], w01 = sW[1][e], w10 = sW[2][e], w11 = sW[3][e];
        #pragma unroll
        for (int i = 0; i < 8; ++i) {
            const float* xc = xb + (size_t)i * Sx;
            float v = w00 * xc[a00] + w01 * xc[a01]
                    + w10 * xc[a10] + w11 * xc[a11];
            vb[i * 9 + chr] = bf16r(v);
        }
    }

    uint4* dst = (uint4*)(xo + ((size_t)(b * 96 + y) * ROWW + (x0b + xl)) * 576 + g * 72);
    #pragma unroll
    for (int a = 0; a < 9; ++a) {
        uint4 u;
        u.x = vb[8*a+0] | ((unsigned)vb[8*a+1] << 16);
        u.y = vb[8*a+2] | ((unsigned)vb[8*a+3] << 16);
        u.z = vb[8*a+4] | ((unsigned)vb[8*a+5] << 16);
        u.w = vb[8*a+6] | ((unsigned)vb[8*a+7] << 16);
        dst[a] = u;
    }
}

// ---- Conv as implicit GEMM on MFMA (unchanged from round 2) ----
__global__ __launch_bounds__(192, 4)
void conv_mfma(const unsigned short* __restrict__ xo,
               const unsigned short* __restrict__ Wb,
               const float* __restrict__ bias,
               float* __restrict__ out) {
    const int lane = threadIdx.x & 63;
    const int wn   = threadIdx.x >> 6;   // 0..2 (= staged ky row)
    const int oy   = blockIdx.x;         // 0..93
    const int b    = blockIdx.y;

    __shared__ unsigned short tile[3 * ROWW * 64];   // 39936 B
    char* tb = (char*)tile;

    f32x4 acc[4][2];
    #pragma unroll
    for (int m = 0; m < 4; ++m)
        #pragma unroll
        for (int nfl = 0; nfl < 2; ++nfl)
            acc[m][nfl] = (f32x4){0.f, 0.f, 0.f, 0.f};

    const bf16x8* W8 = (const bf16x8*)Wb;

    const int xl  = lane >> 3;          // 0..7
    const int sl  = lane & 7;
    const int swz = (sl ^ xl) * 8;      // pre-swizzled q-slot (elems)
    const size_t growbase = ((size_t)(b * 96 + oy + wn) * ROWW) * 576;
    unsigned short* lrow = tile + wn * (ROWW * 64);   // this wave stages row ky=wn

    for (int qc = 0; qc < 9; ++qc) {
        if (qc) __syncthreads();
        #pragma unroll
        for (int i = 0; i < 13; ++i) {
            const unsigned short* src =
                xo + growbase + (size_t)(i * 8 + xl) * 576 + qc * 64 + swz;
            gload16(src, lrow + i * 512);   // + lane*16B implicit
        }
        asm volatile("s_waitcnt vmcnt(0)" ::: "memory");
        __syncthreads();

        #pragma unroll
        for (int t = 0; t < 9; ++t) {
            const int ky = t / 3, kx = t - (t / 3) * 3;
            #pragma unroll
            for (int q32 = 0; q32 < 2; ++q32) {
                const int step = qc * 18 + t * 2 + q32;
                bf16x8 a0 = W8[(step * 4 + 0) * 64 + lane];
                bf16x8 a1 = W8[(step * 4 + 1) * 64 + lane];
                bf16x8 a2 = W8[(step * 4 + 2) * 64 + lane];
                bf16x8 a3 = W8[(step * 4 + 3) * 64 + lane];
                bf16x8 bf[2];
                #pragma unroll
                for (int nfl = 0; nfl < 2; ++nfl) {
                    int xpix = (wn * 2 + nfl) * 16 + (lane & 15) + kx;
                    int slot = (q32 * 4 + (lane >> 4)) ^ (xpix & 7);
                    bf[nfl] = *(const bf16x8*)(tb + ky * 13312 + xpix * 128 + slot * 16);
                }
                acc[0][0] = __builtin_amdgcn_mfma_f32_16x16x32_bf16(a0, bf[0], acc[0][0], 0, 0, 0);
                acc[0][1] = __builtin_amdgcn_mfma_f32_16x16x32_bf16(a0, bf[1], acc[0][1], 0, 0, 0);
                acc[1][0] = __builtin_amdgcn_mfma_f32_16x16x32_bf16(a1, bf[0], acc[1][0], 0, 0, 0);
                acc[1][1] = __builtin_amdgcn_mfma_f32_16x16x32_bf16(a1, bf[1], acc[1][1], 0, 0, 0);
                acc[2][0] = __builtin_amdgcn_mfma_f32_16x16x32_bf16(a2, bf[0], acc[2][0], 0, 0, 0);
                acc[2][1] = __builtin_amdgcn_mfma_f32_16x16x32_bf16(a2, bf[1], acc[2][1], 0, 0, 0);
                acc[3][0] = __builtin_amdgcn_mfma_f32_16x16x32_bf16(a3, bf[0], acc[3][0], 0, 0, 0);
                acc[3][1] = __builtin_amdgcn_mfma_f32_16x16x32_bf16(a3, bf[1], acc[3][1], 0, 0, 0);
            }
        }
    }

    // Epilogue: C/D layout col=lane&15 (pixel), row=(lane>>4)*4+j (o in tile)
    #pragma unroll
    for (int m = 0; m < 4; ++m) {
        #pragma unroll
        for (int nfl = 0; nfl < 2; ++nfl) {
            int ox = (wn * 2 + nfl) * 16 + (lane & 15);
            if (ox < OW) {
                #pragma unroll
                for (int j = 0; j < 4; ++j) {
                    int o = m * 16 + (lane >> 4) * 4 + j;
                    out[(((size_t)b * 64 + o) * OW + oy) * OW + ox] = acc[m][nfl][j] + bias[o];
                }
            }
        }
    }
}

extern "C" void kernel_launch(void* const* d_in, const int* in_sizes, int n_in,
                              void* d_out, int out_size, void* d_ws, size_t ws_size,
                              hipStream_t stream) {
    const float* x    = (const float*)d_in[0];
    const float* off  = (const float*)d_in[1];
    const float* w    = (const float*)d_in[2];
    const float* bias = (const float*)d_in[3];
    unsigned short* ws16 = (unsigned short*)d_ws;
    unsigned short* Wb   = ws16;                  // 663,552 B
    unsigned short* xo   = ws16 + WB_USHORTS;     // 8*96*104*576*2 = 92.0 MB

    wprep_k<<<162, 256, 0, stream>>>(w, Wb);
    gather_k<<<dim3(3, 96, 8), 256, 0, stream>>>(x, off, xo);
    conv_mfma<<<dim3(94, 8), 192, 0, stream>>>(xo, Wb, bias, (float*)d_out);
}

// Round 4
// 287.407 us; speedup vs baseline: 9.5633x; 1.0142x over previous
//
#include <hip/hip_runtime.h>

typedef short bf16x8 __attribute__((ext_vector_type(8)));
typedef float f32x4  __attribute__((ext_vector_type(4)));

#define Sx 9216          // 96*96
#define ROWW 104         // padded x width of xo_t
#define WB_USHORTS 331776    // 162 steps * 4 mt * 64 lanes * 8
#define OW 94

__device__ __forceinline__ unsigned short bf16r(float f) {
    unsigned int u = __float_as_uint(f);
    u += 0x7fffu + ((u >> 16) & 1u);
    return (unsigned short)(u >> 16);
}

__device__ __forceinline__ void gload16(const void* g, void* l) {
    __builtin_amdgcn_global_load_lds(
        (const __attribute__((address_space(1))) void*)g,
        (__attribute__((address_space(3))) void*)l, 16, 0, 0);
}

// ---- Weight prep: fp32 conv_w -> bf16 in MFMA A-fragment order ----
// K-dim uses the PERMUTED channel order q' = chr*64 + ci  (chr==qc chunk).
// Element (step=qc*18+t*2+q32, mt, lane, j):
//   o = mt*16 + (lane&15), ci = q32*32 + (lane>>4)*8 + j, chr = qc, tap t
//   original weight index q_orig = ci*9 + chr
__global__ __launch_bounds__(256)
void wprep_k(const float* __restrict__ w, unsigned short* __restrict__ Wb) {
    int id = blockIdx.x * 256 + threadIdx.x;       // 0..41471
    if (id >= 162 * 4 * 64) return;
    int lane = id & 63;
    int fm   = id >> 6;          // step*4 + mt
    int mt   = fm & 3;
    int step = fm >> 2;
    int qc   = step / 18;
    int rs   = step - qc * 18;
    int t    = rs >> 1;
    int q32  = rs & 1;
    int o    = mt * 16 + (lane & 15);
    int cib  = q32 * 32 + (lane >> 4) * 8;
    unsigned short v[8];
    #pragma unroll
    for (int j = 0; j < 8; ++j) {
        int qorig = (cib + j) * 9 + qc;
        v[j] = bf16r(w[(size_t)o * 5184 + qorig * 9 + t]);
    }
    uint4 u;
    u.x = v[0] | ((unsigned)v[1] << 16);
    u.y = v[2] | ((unsigned)v[3] << 16);
    u.z = v[4] | ((unsigned)v[5] << 16);
    u.w = v[6] | ((unsigned)v[7] << 16);
    *(uint4*)(Wb + (size_t)id * 8) = u;
}

// ---- Gather -> xo_t[b][y][x(104)][q'(576)] bf16, q' = chr*64 + ci ----
// Phase 1: shared decode table (4 addrs + 4 fused weights per (chr,x)).
// Phase 2: per chr: 32 independent 4B loads -> 8 values -> ONE uint4 store.
__global__ __launch_bounds__(256, 2)
void gather_k(const float* __restrict__ x, const float* __restrict__ off,
              unsigned short* __restrict__ xo) {
    __shared__ int   sA[4][288];
    __shared__ float sW[4][288];

    const int tid = threadIdx.x;
    const int x0b = blockIdx.x * 32;
    const int y   = blockIdx.y;
    const int b   = blockIdx.z;
    const float* ob = off + (size_t)b * 18 * Sx;

    // ---- phase 1: decode 288 entries (chr 0..8  x  32 x-positions) ----
    for (int e = tid; e < 288; e += 256) {
        int chr = e >> 5;
        int xl  = e & 31;
        int r2  = y * 96 + x0b + xl;
        int n   = r2 % 9;                 // 9216 % 9 == 0
        int r   = chr * 1024 + r2 / 9;
        float q2[2];
        #pragma unroll
        for (int c2 = 0; c2 < 2; ++c2) {
            int k    = n + 9 * c2;
            int f    = k * Sx + r;
            int nn   = f / 18432;
            int t    = f - nn * 18432;
            int comp = t & 1;
            int pos  = t >> 1;
            int nd3  = nn / 3;
            float gg = comp ? (float)(nn - nd3 * 3) : (float)nd3;
            q2[c2] = gg + ob[(size_t)(2 * nn + comp) * Sx + pos];
        }
        float qx = fminf(fmaxf(q2[0], 0.f), 97.f);
        float qy = fminf(fmaxf(q2[1], 0.f), 97.f);
        int x0 = (int)qx; if (x0 > 97) x0 = 97;
        int y0 = (int)qy; if (y0 > 97) y0 = 97;
        float fx = qx - (float)x0;
        float fy = qy - (float)y0;
        int x1 = x0 + 1; if (x1 > 97) x1 = 97;
        int y1 = y0 + 1; if (y1 > 97) y1 = 97;
        int ix0 = x0 - 1, ix1 = x1 - 1, iy0 = y0 - 1, iy1 = y1 - 1;
        float vx0 = (ix0 >= 0 && ix0 < 96) ? 1.f : 0.f;
        float vx1 = (ix1 >= 0 && ix1 < 96) ? 1.f : 0.f;
        float vy0 = (iy0 >= 0 && iy0 < 96) ? 1.f : 0.f;
        float vy1 = (iy1 >= 0 && iy1 < 96) ? 1.f : 0.f;
        int cx0 = min(max(ix0, 0), 95), cx1 = min(max(ix1, 0), 95);
        int cy0 = min(max(iy0, 0), 95), cy1 = min(max(iy1, 0), 95);
        sW[0][e] = (1.f - fx) * (1.f - fy) * vx0 * vy0;
        sW[1][e] = fx * (1.f - fy) * vx1 * vy0;
        sW[2][e] = (1.f - fx) * fy * vx0 * vy1;
        sW[3][e] = fx * fy * vx1 * vy1;
        sA[0][e] = cy0 * 96 + cx0;
        sA[1][e] = cy0 * 96 + cx1;
        sA[2][e] = cy1 * 96 + cx0;
        sA[3][e] = cy1 * 96 + cx1;
    }
    __syncthreads();

    // ---- phase 2 ----
    const int xl = tid & 31;
    const int g  = tid >> 5;
    const float* xb = x + (size_t)b * 64 * Sx + (size_t)g * 8 * Sx;
    uint4* dst = (uint4*)(xo + ((size_t)(b * 96 + y) * ROWW + (x0b + xl)) * 576) + g;

    #pragma unroll
    for (int chr = 0; chr < 9; ++chr) {
        int e = chr * 32 + xl;
        int   a00 = sA[0][e], a01 = sA[1][e], a10 = sA[2][e], a11 = sA[3][e];
        float w00 = sW[0][e], w01 = sW[1][e], w10 = sW[2][e], w11 = sW[3][e];
        unsigned short v[8];
        #pragma unroll
        for (int i = 0; i < 8; ++i) {
            const float* xc = xb + (size_t)i * Sx;
            v[i] = bf16r(w00 * xc[a00] + w01 * xc[a01]
                       + w10 * xc[a10] + w11 * xc[a11]);
        }
        uint4 u;
        u.x = v[0] | ((unsigned)v[1] << 16);
        u.y = v[2] | ((unsigned)v[3] << 16);
        u.z = v[4] | ((unsigned)v[5] << 16);
        u.w = v[6] | ((unsigned)v[7] << 16);
        dst[chr * 8] = u;    // q' = chr*64 + g*8
    }
}

// ---- Conv as implicit GEMM on MFMA (positional pairing — unchanged) ----
__global__ __launch_bounds__(192, 4)
void conv_mfma(const unsigned short* __restrict__ xo,
               const unsigned short* __restrict__ Wb,
               const float* __restrict__ bias,
               float* __restrict__ out) {
    const int lane = threadIdx.x & 63;
    const int wn   = threadIdx.x >> 6;   // 0..2 (= staged ky row)
    const int oy   = blockIdx.x;         // 0..93
    const int b    = blockIdx.y;

    __shared__ unsigned short tile[3 * ROWW * 64];   // 39936 B
    char* tb = (char*)tile;

    f32x4 acc[4][2];
    #pragma unroll
    for (int m = 0; m < 4; ++m)
        #pragma unroll
        for (int nfl = 0; nfl < 2; ++nfl)
            acc[m][nfl] = (f32x4){0.f, 0.f, 0.f, 0.f};

    const bf16x8* W8 = (const bf16x8*)Wb;

    const int xl  = lane >> 3;          // 0..7
    const int sl  = lane & 7;
    const int swz = (sl ^ xl) * 8;      // pre-swizzled q-slot (elems)
    const size_t growbase = ((size_t)(b * 96 + oy + wn) * ROWW) * 576;
    unsigned short* lrow = tile + wn * (ROWW * 64);   // this wave stages row ky=wn

    for (int qc = 0; qc < 9; ++qc) {
        if (qc) __syncthreads();
        #pragma unroll
        for (int i = 0; i < 13; ++i) {
            const unsigned short* src =
                xo + growbase + (size_t)(i * 8 + xl) * 576 + qc * 64 + swz;
            gload16(src, lrow + i * 512);   // + lane*16B implicit
        }
        asm volatile("s_waitcnt vmcnt(0)" ::: "memory");
        __syncthreads();

        #pragma unroll
        for (int t = 0; t < 9; ++t) {
            const int ky = t / 3, kx = t - (t / 3) * 3;
            #pragma unroll
            for (int q32 = 0; q32 < 2; ++q32) {
                const int step = qc * 18 + t * 2 + q32;
                bf16x8 a0 = W8[(step * 4 + 0) * 64 + lane];
                bf16x8 a1 = W8[(step * 4 + 1) * 64 + lane];
                bf16x8 a2 = W8[(step * 4 + 2) * 64 + lane];
                bf16x8 a3 = W8[(step * 4 + 3) * 64 + lane];
                bf16x8 bf[2];
                #pragma unroll
                for (int nfl = 0; nfl < 2; ++nfl) {
                    int xpix = (wn * 2 + nfl) * 16 + (lane & 15) + kx;
                    int slot = (q32 * 4 + (lane >> 4)) ^ (xpix & 7);
                    bf[nfl] = *(const bf16x8*)(tb + ky * 13312 + xpix * 128 + slot * 16);
                }
                acc[0][0] = __builtin_amdgcn_mfma_f32_16x16x32_bf16(a0, bf[0], acc[0][0], 0, 0, 0);
                acc[0][1] = __builtin_amdgcn_mfma_f32_16x16x32_bf16(a0, bf[1], acc[0][1], 0, 0, 0);
                acc[1][0] = __builtin_amdgcn_mfma_f32_16x16x32_bf16(a1, bf[0], acc[1][0], 0, 0, 0);
                acc[1][1] = __builtin_amdgcn_mfma_f32_16x16x32_bf16(a1, bf[1], acc[1][1], 0, 0, 0);
                acc[2][0] = __builtin_amdgcn_mfma_f32_16x16x32_bf16(a2, bf[0], acc[2][0], 0, 0, 0);
                acc[2][1] = __builtin_amdgcn_mfma_f32_16x16x32_bf16(a2, bf[1], acc[2][1], 0, 0, 0);
                acc[3][0] = __builtin_amdgcn_mfma_f32_16x16x32_bf16(a3, bf[0], acc[3][0], 0, 0, 0);
                acc[3][1] = __builtin_amdgcn_mfma_f32_16x16x32_bf16(a3, bf[1], acc[3][1], 0, 0, 0);
            }
        }
    }

    // Epilogue: C/D layout col=lane&15 (pixel), row=(lane>>4)*4+j (o in tile)
    #pragma unroll
    for (int m = 0; m < 4; ++m) {
        #pragma unroll
        for (int nfl = 0; nfl < 2; ++nfl) {
            int ox = (wn * 2 + nfl) * 16 + (lane & 15);
            if (ox < OW) {
                #pragma unroll
                for (int j = 0; j < 4; ++j) {
                    int o = m * 16 + (lane >> 4) * 4 + j;
                    out[(((size_t)b * 64 + o) * OW + oy) * OW + ox] = acc[m][nfl][j] + bias[o];
                }
            }
        }
    }
}

extern "C" void kernel_launch(void* const* d_in, const int* in_sizes, int n_in,
                              void* d_out, int out_size, void* d_ws, size_t ws_size,
                              hipStream_t stream) {
    const float* x    = (const float*)d_in[0];
    const float* off  = (const float*)d_in[1];
    const float* w    = (const float*)d_in[2];
    const float* bias = (const float*)d_in[3];
    unsigned short* ws16 = (unsigned short*)d_ws;
    unsigned short* Wb   = ws16;                  // 663,552 B
    unsigned short* xo   = ws16 + WB_USHORTS;     // 8*96*104*576*2 = 92.0 MB

    wprep_k<<<162, 256, 0, stream>>>(w, Wb);
    gather_k<<<dim3(3, 96, 8), 256, 0, stream>>>(x, off, xo);
    conv_mfma<<<dim3(94, 8), 192, 0, stream>>>(xo, Wb, bias, (float*)d_out);
}

// Round 5
// 161.436 us; speedup vs baseline: 17.0256x; 1.7803x over previous
//
#include <hip/hip_runtime.h>

typedef short bf16x8 __attribute__((ext_vector_type(8)));
typedef float f32x4  __attribute__((ext_vector_type(4)));

#define Sx 9216              // 96*96
#define ROWW 96              // x width of xo_t (12 staging iters x 8)
#define WB_USHORTS 331776    // 162 steps * 4 mt * 64 lanes * 8
#define OW 94
#define XO_USHORTS ((size_t)8 * 96 * ROWW * 576)         // 42,467,328
#define XT_OFF_BYTES (2 * (size_t)WB_USHORTS + 2 * XO_USHORTS) // 85,598,208
#define NEED_NEW (XT_OFF_BYTES + (size_t)8 * Sx * 64 * 4)      // 104,472,576

__device__ __forceinline__ unsigned short bf16r(float f) {
    unsigned int u = __float_as_uint(f);
    u += 0x7fffu + ((u >> 16) & 1u);
    return (unsigned short)(u >> 16);
}

__device__ __forceinline__ void gload16(const void* g, void* l) {
    __builtin_amdgcn_global_load_lds(
        (const __attribute__((address_space(1))) void*)g,
        (__attribute__((address_space(3))) void*)l, 16, 0, 0);
}

// ---- Weight prep: fp32 conv_w -> bf16, K permuted as q' = chr*64 + ci ----
__global__ __launch_bounds__(256)
void wprep_k(const float* __restrict__ w, unsigned short* __restrict__ Wb) {
    int id = blockIdx.x * 256 + threadIdx.x;       // 0..41471
    if (id >= 162 * 4 * 64) return;
    int lane = id & 63;
    int fm   = id >> 6;          // step*4 + mt
    int mt   = fm & 3;
    int step = fm >> 2;
    int qc   = step / 18;
    int rs   = step - qc * 18;
    int t    = rs >> 1;
    int q32  = rs & 1;
    int o    = mt * 16 + (lane & 15);
    int cib  = q32 * 32 + (lane >> 4) * 8;
    unsigned short v[8];
    #pragma unroll
    for (int j = 0; j < 8; ++j) {
        int qorig = (cib + j) * 9 + qc;
        v[j] = bf16r(w[(size_t)o * 5184 + qorig * 9 + t]);
    }
    uint4 u;
    u.x = v[0] | ((unsigned)v[1] << 16);
    u.y = v[2] | ((unsigned)v[3] << 16);
    u.z = v[4] | ((unsigned)v[5] << 16);
    u.w = v[6] | ((unsigned)v[7] << 16);
    *(uint4*)(Wb + (size_t)id * 8) = u;
}

// ---- Transpose x: [b][ci][pos] -> xt [b][pos][ci]  (channel-last) ----
__global__ __launch_bounds__(256)
void xt_k(const float* __restrict__ x, float* __restrict__ xt) {
    __shared__ float t[64][65];
    const int tid = threadIdx.x;
    const int r2b = blockIdx.x * 64;
    const int b   = blockIdx.y;
    const int qq  = tid >> 6;      // 0..3
    const int ll  = tid & 63;
    #pragma unroll
    for (int cc = 0; cc < 16; ++cc) {
        int ci = cc * 4 + qq;
        t[ci][ll] = x[((size_t)(b * 64 + ci)) * Sx + r2b + ll];
    }
    __syncthreads();
    #pragma unroll
    for (int rr = 0; rr < 16; ++rr) {
        int r2l = rr * 4 + qq;
        xt[((size_t)b * Sx + r2b + r2l) * 64 + ll] = t[ll][r2l];
    }
}

// ---- Shared decode (phase 1 of both gather variants) ----
__device__ __forceinline__ void decode_phase1(
        const float* __restrict__ ob, int x0b, int y,
        int (*sA)[288], float (*sW)[288], int tid) {
    for (int e = tid; e < 288; e += 256) {
        int chr = e >> 5;
        int xl  = e & 31;
        int r2  = y * 96 + x0b + xl;
        int n   = r2 % 9;                 // 9216 % 9 == 0
        int r   = chr * 1024 + r2 / 9;
        float q2[2];
        #pragma unroll
        for (int c2 = 0; c2 < 2; ++c2) {
            int k    = n + 9 * c2;
            int f    = k * Sx + r;
            int nn   = f / 18432;
            int t    = f - nn * 18432;
            int comp = t & 1;
            int pos  = t >> 1;
            int nd3  = nn / 3;
            float gg = comp ? (float)(nn - nd3 * 3) : (float)nd3;
            q2[c2] = gg + ob[(size_t)(2 * nn + comp) * Sx + pos];
        }
        float qx = fminf(fmaxf(q2[0], 0.f), 97.f);
        float qy = fminf(fmaxf(q2[1], 0.f), 97.f);
        int x0 = (int)qx; if (x0 > 97) x0 = 97;
        int y0 = (int)qy; if (y0 > 97) y0 = 97;
        float fx = qx - (float)x0;
        float fy = qy - (float)y0;
        int x1 = x0 + 1; if (x1 > 97) x1 = 97;
        int y1 = y0 + 1; if (y1 > 97) y1 = 97;
        int ix0 = x0 - 1, ix1 = x1 - 1, iy0 = y0 - 1, iy1 = y1 - 1;
        float vx0 = (ix0 >= 0 && ix0 < 96) ? 1.f : 0.f;
        float vx1 = (ix1 >= 0 && ix1 < 96) ? 1.f : 0.f;
        float vy0 = (iy0 >= 0 && iy0 < 96) ? 1.f : 0.f;
        float vy1 = (iy1 >= 0 && iy1 < 96) ? 1.f : 0.f;
        int cx0 = min(max(ix0, 0), 95), cx1 = min(max(ix1, 0), 95);
        int cy0 = min(max(iy0, 0), 95), cy1 = min(max(iy1, 0), 95);
        sW[0][e] = (1.f - fx) * (1.f - fy) * vx0 * vy0;
        sW[1][e] = fx * (1.f - fy) * vx1 * vy0;
        sW[2][e] = (1.f - fx) * fy * vx0 * vy1;
        sW[3][e] = fx * fy * vx1 * vy1;
        sA[0][e] = cy0 * 96 + cx0;
        sA[1][e] = cy0 * 96 + cx1;
        sA[2][e] = cy1 * 96 + cx0;
        sA[3][e] = cy1 * 96 + cx1;
    }
}

// ---- Gather (new): wave-per-entry, coalesced taps from channel-last xt ----
__global__ __launch_bounds__(256, 4)
void gather_xt(const float* __restrict__ xt, const float* __restrict__ off,
               unsigned short* __restrict__ xo) {
    __shared__ int   sA[4][288];
    __shared__ float sW[4][288];
    const int tid = threadIdx.x;
    const int x0b = blockIdx.x * 32;
    const int y   = blockIdx.y;
    const int b   = blockIdx.z;
    decode_phase1(off + (size_t)b * 18 * Sx, x0b, y, sA, sW, tid);
    __syncthreads();

    const int lane = tid & 63;
    const int wv   = tid >> 6;
    const float* xtb = xt + (size_t)b * Sx * 64 + lane;
    unsigned short* xob =
        xo + ((size_t)(b * 96 + y) * ROWW + x0b) * 576 + lane;

    #pragma unroll 4
    for (int i = 0; i < 72; ++i) {
        int e   = wv * 72 + i;
        int chr = e >> 5;
        int xl  = e & 31;
        float v = sW[0][e] * xtb[(size_t)sA[0][e] * 64]
                + sW[1][e] * xtb[(size_t)sA[1][e] * 64]
                + sW[2][e] * xtb[(size_t)sA[2][e] * 64]
                + sW[3][e] * xtb[(size_t)sA[3][e] * 64];
        xob[xl * 576 + chr * 64] = bf16r(v);
    }
}

// ---- Gather (fallback, round-4 path; used only if ws too small) ----
__global__ __launch_bounds__(256, 2)
void gather_fb(const float* __restrict__ x, const float* __restrict__ off,
               unsigned short* __restrict__ xo) {
    __shared__ int   sA[4][288];
    __shared__ float sW[4][288];
    const int tid = threadIdx.x;
    const int x0b = blockIdx.x * 32;
    const int y   = blockIdx.y;
    const int b   = blockIdx.z;
    decode_phase1(off + (size_t)b * 18 * Sx, x0b, y, sA, sW, tid);
    __syncthreads();

    const int xl = tid & 31;
    const int g  = tid >> 5;
    const float* xb = x + (size_t)b * 64 * Sx + (size_t)g * 8 * Sx;
    uint4* dst = (uint4*)(xo + ((size_t)(b * 96 + y) * ROWW + (x0b + xl)) * 576) + g;

    #pragma unroll
    for (int chr = 0; chr < 9; ++chr) {
        int e = chr * 32 + xl;
        int   a00 = sA[0][e], a01 = sA[1][e], a10 = sA[2][e], a11 = sA[3][e];
        float w00 = sW[0][e], w01 = sW[1][e], w10 = sW[2][e], w11 = sW[3][e];
        unsigned short v[8];
        #pragma unroll
        for (int i = 0; i < 8; ++i) {
            const float* xc = xb + (size_t)i * Sx;
            v[i] = bf16r(w00 * xc[a00] + w01 * xc[a01]
                       + w10 * xc[a10] + w11 * xc[a11]);
        }
        uint4 u;
        u.x = v[0] | ((unsigned)v[1] << 16);
        u.y = v[2] | ((unsigned)v[3] << 16);
        u.z = v[4] | ((unsigned)v[5] << 16);
        u.w = v[6] | ((unsigned)v[7] << 16);
        dst[chr * 8] = u;    // q' = chr*64 + g*8
    }
}

// ---- Conv as implicit GEMM on MFMA (ROWW=96, 12 staging iters) ----
__global__ __launch_bounds__(192, 4)
void conv_mfma(const unsigned short* __restrict__ xo,
               const unsigned short* __restrict__ Wb,
               const float* __restrict__ bias,
               float* __restrict__ out) {
    const int lane = threadIdx.x & 63;
    const int wn   = threadIdx.x >> 6;   // 0..2 (= staged ky row)
    const int oy   = blockIdx.x;         // 0..93
    const int b    = blockIdx.y;

    __shared__ unsigned short tile[3 * ROWW * 64 + 128];  // +256B pad: xpix 96/97
    char* tb = (char*)tile;                               // reads (masked cols) stay in-bounds

    f32x4 acc[4][2];
    #pragma unroll
    for (int m = 0; m < 4; ++m)
        #pragma unroll
        for (int nfl = 0; nfl < 2; ++nfl)
            acc[m][nfl] = (f32x4){0.f, 0.f, 0.f, 0.f};

    const bf16x8* W8 = (const bf16x8*)Wb;

    const int xl  = lane >> 3;          // 0..7
    const int sl  = lane & 7;
    const int swz = (sl ^ xl) * 8;      // pre-swizzled q-slot (elems)
    const size_t growbase = (size_t)(b * 96 + oy + wn) * (ROWW * 576);
    unsigned short* lrow = tile + wn * (ROWW * 64);   // this wave stages row ky=wn

    for (int qc = 0; qc < 9; ++qc) {
        if (qc) __syncthreads();
        #pragma unroll
        for (int i = 0; i < 12; ++i) {
            const unsigned short* src =
                xo + growbase + (size_t)(i * 8 + xl) * 576 + qc * 64 + swz;
            gload16(src, lrow + i * 512);   // + lane*16B implicit
        }
        asm volatile("s_waitcnt vmcnt(0)" ::: "memory");
        __syncthreads();

        #pragma unroll
        for (int t = 0; t < 9; ++t) {
            const int ky = t / 3, kx = t - (t / 3) * 3;
            #pragma unroll
            for (int q32 = 0; q32 < 2; ++q32) {
                const int step = qc * 18 + t * 2 + q32;
                bf16x8 a0 = W8[(step * 4 + 0) * 64 + lane];
                bf16x8 a1 = W8[(step * 4 + 1) * 64 + lane];
                bf16x8 a2 = W8[(step * 4 + 2) * 64 + lane];
                bf16x8 a3 = W8[(step * 4 + 3) * 64 + lane];
                bf16x8 bf[2];
                #pragma unroll
                for (int nfl = 0; nfl < 2; ++nfl) {
                    int xpix = (wn * 2 + nfl) * 16 + (lane & 15) + kx;
                    int slot = (q32 * 4 + (lane >> 4)) ^ (xpix & 7);
                    bf[nfl] = *(const bf16x8*)(tb + ky * (ROWW * 128) + xpix * 128 + slot * 16);
                }
                acc[0][0] = __builtin_amdgcn_mfma_f32_16x16x32_bf16(a0, bf[0], acc[0][0], 0, 0, 0);
                acc[0][1] = __builtin_amdgcn_mfma_f32_16x16x32_bf16(a0, bf[1], acc[0][1], 0, 0, 0);
                acc[1][0] = __builtin_amdgcn_mfma_f32_16x16x32_bf16(a1, bf[0], acc[1][0], 0, 0, 0);
                acc[1][1] = __builtin_amdgcn_mfma_f32_16x16x32_bf16(a1, bf[1], acc[1][1], 0, 0, 0);
                acc[2][0] = __builtin_amdgcn_mfma_f32_16x16x32_bf16(a2, bf[0], acc[2][0], 0, 0, 0);
                acc[2][1] = __builtin_amdgcn_mfma_f32_16x16x32_bf16(a2, bf[1], acc[2][1], 0, 0, 0);
                acc[3][0] = __builtin_amdgcn_mfma_f32_16x16x32_bf16(a3, bf[0], acc[3][0], 0, 0, 0);
                acc[3][1] = __builtin_amdgcn_mfma_f32_16x16x32_bf16(a3, bf[1], acc[3][1], 0, 0, 0);
            }
        }
    }

    // Epilogue: C/D layout col=lane&15 (pixel), row=(lane>>4)*4+j (o in tile)
    #pragma unroll
    for (int m = 0; m < 4; ++m) {
        #pragma unroll
        for (int nfl = 0; nfl < 2; ++nfl) {
            int ox = (wn * 2 + nfl) * 16 + (lane & 15);
            if (ox < OW) {
                #pragma unroll
                for (int j = 0; j < 4; ++j) {
                    int o = m * 16 + (lane >> 4) * 4 + j;
                    out[(((size_t)b * 64 + o) * OW + oy) * OW + ox] = acc[m][nfl][j] + bias[o];
                }
            }
        }
    }
}

extern "C" void kernel_launch(void* const* d_in, const int* in_sizes, int n_in,
                              void* d_out, int out_size, void* d_ws, size_t ws_size,
                              hipStream_t stream) {
    const float* x    = (const float*)d_in[0];
    const float* off  = (const float*)d_in[1];
    const float* w    = (const float*)d_in[2];
    const float* bias = (const float*)d_in[3];
    unsigned short* ws16 = (unsigned short*)d_ws;
    unsigned short* Wb   = ws16;                  // 663,552 B
    unsigned short* xo   = ws16 + WB_USHORTS;     // 84.9 MB

    wprep_k<<<162, 256, 0, stream>>>(w, Wb);
    if (ws_size >= NEED_NEW) {
        float* xt = (float*)((char*)d_ws + XT_OFF_BYTES);   // 18.9 MB
        xt_k<<<dim3(144, 8), 256, 0, stream>>>(x, xt);
        gather_xt<<<dim3(3, 96, 8), 256, 0, stream>>>(xt, off, xo);
    } else {
        gather_fb<<<dim3(3, 96, 8), 256, 0, stream>>>(x, off, xo);
    }
    conv_mfma<<<dim3(94, 8), 192, 0, stream>>>(xo, Wb, bias, (float*)d_out);
}